// Round 11
// baseline (72.259 us; speedup 1.0000x reference)
//
#include <hip/hip_runtime.h>

#define T_WPAD  962048   // reflect-padded waveform length (before zero tail)
#define T_RAW   960000
#define NFRM    1879
#define OUTW    1876
#define MEDLEN  1864
#define WINL    30
#define PADL    14
#define FPB     8        // frames per block
#define NBX     235      // ceil(NFRM / FPB)
#define XLEN    4296     // 7*512 + 705 + pad (float4-divisible)
#define X4LEN   1074

// ---------------- Kernel 1: NCCF + per-frame lag selection ----------------
// 128 thr = 2 waves; each wave handles FOUR frames (one per 16-lane group).
// g = lane>>4 picks frame-in-wave, s = lane&15 owns lags 12s+1..12s+12.
// SPLIT-K ILP: each lane runs TWO independent sliding-window chains
// (j in [0,256) and [256,512)) so FMA issue overlaps the other chain's
// ds_read latency. Per iter: 4 ds_read_b128 + 96 FMA ops (same totals as
// the single-chain version, 2x the independent work). Norms in-stream (f64
// running quad-sums). LDS = signal tile only (17.2 KB).
__global__ __launch_bounds__(128) void nccf_kernel(const float* __restrict__ wav,
                                                   int* __restrict__ idxArr) {
    const int bx   = blockIdx.x;
    const int b    = blockIdx.y;
    const int tid  = threadIdx.x;
    const int wave = tid >> 6;           // 0..1
    const int lane = tid & 63;
    const int g    = lane >> 4;          // frame within wave (0..3)
    const int s    = lane & 15;          // lag-group lane (0..15)

    __shared__ __align__(16) float X[XLEN];

    const long a0 = (long)bx * (FPB * 512);
    const float* wrow = wav + (long)b * T_RAW;

    // Stage wp[a0 .. a0+XLEN): vectorized fast path for interior blocks.
    if (bx >= 1 && bx <= NBX - 2) {
        const float4* src = (const float4*)(wrow + (a0 - 1024));
        float4* dst = (float4*)X;
        for (int i = tid; i < X4LEN; i += 128) dst[i] = src[i];
    } else {
        for (int i = tid; i < XLEN; i += 128) {
            float v = 0.0f;
            long t = a0 + i;
            if (t < T_WPAD) {
                long u = t - 1024;
                if (u < 0) u = -u;
                if (u >= T_RAW) u = 2L * (T_RAW - 1) - u;
                v = wrow[u];
            }
            X[i] = v;
        }
    }
    __syncthreads();

    const int F  = wave * 4 + g;         // frame within block (0..7)
    const int gf = bx * FPB + F;         // global frame
    const bool valid = (gf < NFRM);

    float accA[12], accB[12];
    #pragma unroll
    for (int r = 0; r < 12; ++r) { accA[r] = 0.0f; accB[r] = 0.0f; }
    float sq[12];                         // squares of X[12s+j], j=0..11
    double TcurA = 0.0, TcurB = 0.0;
    float wA[16], wB[16];

    {
        const float4* X4 = (const float4*)X;
        const int aBase = F * 128;            // float4 index of Xf[0]
        const int wBase = aBase + 3 * s;      // float4 index of Xf[12s]
        #pragma unroll
        for (int d = 0; d < 4; ++d) {
            float4 tA = X4[wBase + d];
            wA[4 * d] = tA.x; wA[4 * d + 1] = tA.y; wA[4 * d + 2] = tA.z; wA[4 * d + 3] = tA.w;
            float4 tB = X4[wBase + 64 + d];
            wB[4 * d] = tB.x; wB[4 * d + 1] = tB.y; wB[4 * d + 2] = tB.z; wB[4 * d + 3] = tB.w;
        }
        #pragma unroll
        for (int j = 0; j < 12; ++j) sq[j] = wA[j] * wA[j];
        #pragma unroll
        for (int j = 0; j < 16; ++j) TcurA += (double)(wA[j] * wA[j]);   // T(16)

        float4 Aa = X4[aBase];
        float4 Ab = X4[aBase + 64];

        // k = 0..59: both chains FMA + both T quads.
        #pragma unroll 4
        for (int k = 0; k < 60; ++k) {
            float4 AnA = X4[aBase + k + 1];
            float4 AnB = X4[aBase + 64 + k + 1];
            float4 nxA = X4[wBase + k + 4];
            float4 nxB = X4[wBase + 64 + k + 4];
            #pragma unroll
            for (int r = 0; r < 12; ++r) {
                accA[r] = fmaf(Aa.x, wA[r + 1], accA[r]);
                accA[r] = fmaf(Aa.y, wA[r + 2], accA[r]);
                accA[r] = fmaf(Aa.z, wA[r + 3], accA[r]);
                accA[r] = fmaf(Aa.w, wA[r + 4], accA[r]);
                accB[r] = fmaf(Ab.x, wB[r + 1], accB[r]);
                accB[r] = fmaf(Ab.y, wB[r + 2], accB[r]);
                accB[r] = fmaf(Ab.z, wB[r + 3], accB[r]);
                accB[r] = fmaf(Ab.w, wB[r + 4], accB[r]);
            }
            float qa = fmaf(nxA.x, nxA.x, fmaf(nxA.y, nxA.y, fmaf(nxA.z, nxA.z, nxA.w * nxA.w)));
            float qb = fmaf(nxB.x, nxB.x, fmaf(nxB.y, nxB.y, fmaf(nxB.z, nxB.z, nxB.w * nxB.w)));
            TcurA += (double)qa;
            TcurB += (double)qb;
            #pragma unroll
            for (int i = 0; i < 12; ++i) { wA[i] = wA[i + 4]; wB[i] = wB[i + 4]; }
            wA[12] = nxA.x; wA[13] = nxA.y; wA[14] = nxA.z; wA[15] = nxA.w;
            wB[12] = nxB.x; wB[13] = nxB.y; wB[14] = nxB.z; wB[15] = nxB.w;
            Aa = AnA; Ab = AnB;
        }
        // k = 60..62: both chains FMA, T quad on chain A only.
        #pragma unroll
        for (int k = 60; k < 63; ++k) {
            float4 AnA = X4[aBase + k + 1];
            float4 AnB = X4[aBase + 64 + k + 1];
            float4 nxA = X4[wBase + k + 4];
            float4 nxB = X4[wBase + 64 + k + 4];
            #pragma unroll
            for (int r = 0; r < 12; ++r) {
                accA[r] = fmaf(Aa.x, wA[r + 1], accA[r]);
                accA[r] = fmaf(Aa.y, wA[r + 2], accA[r]);
                accA[r] = fmaf(Aa.z, wA[r + 3], accA[r]);
                accA[r] = fmaf(Aa.w, wA[r + 4], accA[r]);
                accB[r] = fmaf(Ab.x, wB[r + 1], accB[r]);
                accB[r] = fmaf(Ab.y, wB[r + 2], accB[r]);
                accB[r] = fmaf(Ab.z, wB[r + 3], accB[r]);
                accB[r] = fmaf(Ab.w, wB[r + 4], accB[r]);
            }
            float qa = fmaf(nxA.x, nxA.x, fmaf(nxA.y, nxA.y, fmaf(nxA.z, nxA.z, nxA.w * nxA.w)));
            TcurA += (double)qa;
            #pragma unroll
            for (int i = 0; i < 12; ++i) { wA[i] = wA[i + 4]; wB[i] = wB[i + 4]; }
            wA[12] = nxA.x; wA[13] = nxA.y; wA[14] = nxA.z; wA[15] = nxA.w;
            wB[12] = nxB.x; wB[13] = nxB.y; wB[14] = nxB.z; wB[15] = nxB.w;
            Aa = AnA; Ab = AnB;
        }
        // k = 63: FMAs only (no shift); plus chain A's last T quad.
        {
            float4 nxA = X4[wBase + 67];      // X[12s+268..272): completes T(272)
            #pragma unroll
            for (int r = 0; r < 12; ++r) {
                accA[r] = fmaf(Aa.x, wA[r + 1], accA[r]);
                accA[r] = fmaf(Aa.y, wA[r + 2], accA[r]);
                accA[r] = fmaf(Aa.z, wA[r + 3], accA[r]);
                accA[r] = fmaf(Aa.w, wA[r + 4], accA[r]);
                accB[r] = fmaf(Ab.x, wB[r + 1], accB[r]);
                accB[r] = fmaf(Ab.y, wB[r + 2], accB[r]);
                accB[r] = fmaf(Ab.z, wB[r + 3], accB[r]);
                accB[r] = fmaf(Ab.w, wB[r + 4], accB[r]);
            }
            float qa = fmaf(nxA.x, nxA.x, fmaf(nxA.y, nxA.y, fmaf(nxA.z, nxA.z, nxA.w * nxA.w)));
            TcurA += (double)qa;
        }
    }
    // wB now holds X[12s+508 .. 12s+524): e_{512+i} = wB[4+i].
    // TcurA = sumsq X[12s..12s+272), TcurB = sumsq X[12s+272..12s+512).
    double T512 = TcurA + TcurB;

    // Epilogue: per-lag norms from registers. q(r) = T(512+r) - T(r).
    double qv[12];
    {
        double Thi = T512, Tlo = 0.0;
        #pragma unroll
        for (int r = 1; r <= 12; ++r) {
            float eh = wB[3 + r];             // X[12s+512+(r-1)]
            Thi += (double)(eh * eh);
            Tlo += (double)sq[r - 1];
            qv[r - 1] = Thi - Tlo;
        }
    }
    double s1d = __shfl(T512, 0, 16);         // frame sumsq P[512] (lane s=0)

    // Per-lane selection over its 12 lags (fp32, np-like first-max ties).
    float bestv = -1e30f, halfv = -1e30f;
    int bestk = 1 << 30, halfk = 1 << 30;
    {
        float s1 = 1e-9f + sqrtf((float)s1d);
        float s1n = s1 * s1;
        #pragma unroll
        for (int r = 1; r <= 12; ++r) {
            int lag  = 12 * s + r;
            int kidx = lag - 1;               // nccf lag index 0..191
            if (kidx <= 188) {
                float s2 = 1e-9f + sqrtf((float)qv[r - 1]);
                float v  = (accA[r - 1] + accB[r - 1]) / s1n / (s2 * s2);
                if (kidx >= 5) {
                    if (v > bestv) { bestv = v; bestk = kidx; }
                    if (kidx <= 93 && v > halfv) { halfv = v; halfk = kidx; }
                }
            }
        }
    }

    // 16-lane (max, first-argmax) reduction for both slices.
    #pragma unroll
    for (int off = 8; off >= 1; off >>= 1) {
        float ov = __shfl_xor(bestv, off, 16); int ok = __shfl_xor(bestk, off, 16);
        if (ov > bestv || (ov == bestv && ok < bestk)) { bestv = ov; bestk = ok; }
        float hv = __shfl_xor(halfv, off, 16); int hk = __shfl_xor(halfk, off, 16);
        if (hv > halfv || (hv == halfv && hk < halfk)) { halfv = hv; halfk = hk; }
    }

    if (valid && s == 0) {
        bool m = (halfv > 0.99f * bestv);
        int sel = m ? halfk : bestk;
        idxArr[b * NFRM + gf] = sel + 1;      // = chosen lag
    }
}

// ---------------- Kernel 2: 30-wide median filter + pitch ----------------
__global__ __launch_bounds__(256) void med_kernel(const int* __restrict__ idxArr,
                                                  float* __restrict__ out) {
    int gid = blockIdx.x * 256 + threadIdx.x;
    if (gid >= 8 * OUTW) return;
    int b = gid / OUTW;
    int i = gid - b * OUTW;
    float o = 0.0f;
    if (i < MEDLEN) {
        const int* row = idxArr + b * NFRM;
        int vals[WINL];
        #pragma unroll
        for (int m = 0; m < WINL; ++m) {
            int sIdx = i + m - PADL;          // left pad = repeat idx[0]
            vals[m] = row[sIdx < 0 ? 0 : sIdx];
        }
        int med = vals[0];
        #pragma unroll
        for (int c = 0; c < WINL; ++c) {
            int cl = 0, ce = 0;
            #pragma unroll
            for (int m = 0; m < WINL; ++m) {
                cl += (vals[m] <  vals[c]) ? 1 : 0;
                ce += (vals[m] == vals[c]) ? 1 : 0;
            }
            if (cl <= 14 && 14 < cl + ce) med = vals[c];   // rank-14 = sorted[14]
        }
        o = 16000.0f / (1e-9f + (float)med);
    }
    out[gid] = o;
}

extern "C" void kernel_launch(void* const* d_in, const int* in_sizes, int n_in,
                              void* d_out, int out_size, void* d_ws, size_t ws_size,
                              hipStream_t stream) {
    const float* wav = (const float*)d_in[0];
    float* out = (float*)d_out;
    int* idxArr = (int*)d_ws;                 // 8*1879 ints = 60128 B

    dim3 gB(NBX, 8);                          // 235 x 8 blocks, 8 frames each
    hipLaunchKernelGGL(nccf_kernel, gB, dim3(128), 0, stream, wav, idxArr);

    int total = 8 * OUTW;
    hipLaunchKernelGGL(med_kernel, dim3((total + 255) / 256), dim3(256), 0, stream,
                       idxArr, out);
}

// Round 12
// 71.401 us; speedup vs baseline: 1.0120x; 1.0120x over previous
//
#include <hip/hip_runtime.h>

#define T_WPAD  962048   // reflect-padded waveform length (before zero tail)
#define T_RAW   960000
#define NFRM    1879
#define OUTW    1876
#define MEDLEN  1864
#define WINL    30
#define PADL    14
#define FPB     8        // frames per block
#define NBX     235      // ceil(NFRM / FPB)
#define XLEN    4296     // 7*512 + 705 + pad (float4-divisible)
#define X4LEN   1074

// ---------------- Kernel 1: NCCF + per-frame lag selection ----------------
// 256 thr = 4 waves; each wave handles TWO frames, split-K across halves:
//   kh = lane>>5  : K-half (j in [0,256) vs [256,512))
//   f  = (lane>>4)&1 : frame within wave
//   s  = lane&15  : owns lags 12s+1..12s+12
// Per iter: 1 ds_read_b128 A (per-16-lane broadcast) + 1 ds_read_b128 nx
// + 48 FMA instrs; 64 iters/wave. Wave count DOUBLES vs R10 (7516 waves,
// ~7.3/SIMD) with identical total instruction counts -> pure TLP gain.
// K-halves merge via __shfl_xor(...,32): no LDS buffers, no barrier.
// Norms in-stream: f64 running quad-sums, S0=[0,256), S1=[256,512).
__global__ __launch_bounds__(256) void nccf_kernel(const float* __restrict__ wav,
                                                   int* __restrict__ idxArr) {
    const int bx   = blockIdx.x;
    const int b    = blockIdx.y;
    const int tid  = threadIdx.x;
    const int wave = tid >> 6;           // 0..3
    const int lane = tid & 63;
    const int kh   = lane >> 5;          // K-half (0/1)
    const int f    = (lane >> 4) & 1;    // frame within wave
    const int s    = lane & 15;          // lag-group lane

    __shared__ __align__(16) float X[XLEN];

    const long a0 = (long)bx * (FPB * 512);
    const float* wrow = wav + (long)b * T_RAW;

    // Stage wp[a0 .. a0+XLEN): vectorized fast path for interior blocks.
    if (bx >= 1 && bx <= NBX - 2) {
        const float4* src = (const float4*)(wrow + (a0 - 1024));
        float4* dst = (float4*)X;
        for (int i = tid; i < X4LEN; i += 256) dst[i] = src[i];
    } else {
        for (int i = tid; i < XLEN; i += 256) {
            float v = 0.0f;
            long t = a0 + i;
            if (t < T_WPAD) {
                long u = t - 1024;
                if (u < 0) u = -u;
                if (u >= T_RAW) u = 2L * (T_RAW - 1) - u;
                v = wrow[u];
            }
            X[i] = v;
        }
    }
    __syncthreads();

    const int F  = wave * 2 + f;         // frame within block (0..7)
    const int gf = bx * FPB + F;         // global frame
    const bool valid = (gf < NFRM);

    float acc[12];
    #pragma unroll
    for (int r = 0; r < 12; ++r) acc[r] = 0.0f;
    float sq[12];                         // X[12s+j]^2, j=0..11 (kh==0 lanes)
    double Tcur = 0.0;                    // this half's sumsq
    float w[16];

    {
        const float4* X4 = (const float4*)X;
        const int aBase = F * 128;                // float4 index of Xf[0]
        const int kOff  = kh << 6;                // 64 float4 = 256 floats
        const int wBase = aBase + 3 * s + kOff;   // window start (12s + 256*kh)
        const int aK    = aBase + kOff;           // A-stream start

        #pragma unroll
        for (int d = 0; d < 4; ++d) {
            float4 t4 = X4[wBase + d];
            w[4 * d] = t4.x; w[4 * d + 1] = t4.y; w[4 * d + 2] = t4.z; w[4 * d + 3] = t4.w;
        }
        #pragma unroll
        for (int j = 0; j < 12; ++j) sq[j] = w[j] * w[j];
        // Tcur init: full 16 window squares (covers [256kh, 256kh+16)).
        #pragma unroll
        for (int j = 0; j < 16; ++j) Tcur += (double)(w[j] * w[j]);

        float4 A = X4[aK];
        // k = 0..59: FMA + T quad (quads cover [256kh+16 .. 256kh+256)).
        #pragma unroll 4
        for (int k = 0; k < 60; ++k) {
            float4 An = X4[aK + k + 1];
            float4 nx = X4[wBase + k + 4];
            #pragma unroll
            for (int r = 0; r < 12; ++r) {
                acc[r] = fmaf(A.x, w[r + 1], acc[r]);
                acc[r] = fmaf(A.y, w[r + 2], acc[r]);
                acc[r] = fmaf(A.z, w[r + 3], acc[r]);
                acc[r] = fmaf(A.w, w[r + 4], acc[r]);
            }
            float quad = fmaf(nx.x, nx.x, fmaf(nx.y, nx.y, fmaf(nx.z, nx.z, nx.w * nx.w)));
            Tcur += (double)quad;
            #pragma unroll
            for (int i = 0; i < 12; ++i) w[i] = w[i + 4];
            w[12] = nx.x; w[13] = nx.y; w[14] = nx.z; w[15] = nx.w;
            A = An;
        }
        // k = 60..62: FMA + shift only (no quad).
        #pragma unroll
        for (int k = 60; k < 63; ++k) {
            float4 An = X4[aK + k + 1];
            float4 nx = X4[wBase + k + 4];
            #pragma unroll
            for (int r = 0; r < 12; ++r) {
                acc[r] = fmaf(A.x, w[r + 1], acc[r]);
                acc[r] = fmaf(A.y, w[r + 2], acc[r]);
                acc[r] = fmaf(A.z, w[r + 3], acc[r]);
                acc[r] = fmaf(A.w, w[r + 4], acc[r]);
            }
            #pragma unroll
            for (int i = 0; i < 12; ++i) w[i] = w[i + 4];
            w[12] = nx.x; w[13] = nx.y; w[14] = nx.z; w[15] = nx.w;
            A = An;
        }
        // k = 63: FMAs only.
        #pragma unroll
        for (int r = 0; r < 12; ++r) {
            acc[r] = fmaf(A.x, w[r + 1], acc[r]);
            acc[r] = fmaf(A.y, w[r + 2], acc[r]);
            acc[r] = fmaf(A.z, w[r + 3], acc[r]);
            acc[r] = fmaf(A.w, w[r + 4], acc[r]);
        }
    }
    // kh==0: w covers X[12s+252..268).  kh==1: w covers X[12s+508..524)
    // (trailing squares e_{512+j} = w[4+j]).  Tcur: S_kh.

    // Cross-half merge via lane^32 shuffles (both sides get the sums).
    double T512 = Tcur + __shfl_xor(Tcur, 32);
    #pragma unroll
    for (int r = 0; r < 12; ++r) acc[r] += __shfl_xor(acc[r], 32);
    float trail[12];
    #pragma unroll
    for (int j = 0; j < 12; ++j) trail[j] = __shfl_xor(w[4 + j], 32);  // kh0 gets kh1's

    // Epilogue (kh==0 lanes produce the result; kh==1 compute garbage safely).
    double qv[12];
    {
        double Thi = T512, Tlo = 0.0;
        #pragma unroll
        for (int r = 1; r <= 12; ++r) {
            float eh = trail[r - 1];          // X[12s+512+(r-1)]
            Thi += (double)(eh * eh);
            Tlo += (double)sq[r - 1];
            qv[r - 1] = Thi - Tlo;
        }
    }
    double s1d = __shfl(T512, 0, 16);         // frame sumsq P[512] (s=0 lane)

    // Per-lane selection over its 12 lags (fp32, np-like first-max ties).
    float bestv = -1e30f, halfv = -1e30f;
    int bestk = 1 << 30, halfk = 1 << 30;
    {
        float s1 = 1e-9f + sqrtf((float)s1d);
        float s1n = s1 * s1;
        #pragma unroll
        for (int r = 1; r <= 12; ++r) {
            int lag  = 12 * s + r;
            int kidx = lag - 1;               // nccf lag index 0..191
            if (kidx <= 188) {
                float s2 = 1e-9f + sqrtf((float)qv[r - 1]);
                float v  = acc[r - 1] / s1n / (s2 * s2);
                if (kidx >= 5) {
                    if (v > bestv) { bestv = v; bestk = kidx; }
                    if (kidx <= 93 && v > halfv) { halfv = v; halfk = kidx; }
                }
            }
        }
    }

    // 16-lane (max, first-argmax) reduction for both slices.
    #pragma unroll
    for (int off = 8; off >= 1; off >>= 1) {
        float ov = __shfl_xor(bestv, off, 16); int ok = __shfl_xor(bestk, off, 16);
        if (ov > bestv || (ov == bestv && ok < bestk)) { bestv = ov; bestk = ok; }
        float hv = __shfl_xor(halfv, off, 16); int hk = __shfl_xor(halfk, off, 16);
        if (hv > halfv || (hv == halfv && hk < halfk)) { halfv = hv; halfk = hk; }
    }

    if (valid && kh == 0 && s == 0) {
        bool m = (halfv > 0.99f * bestv);
        int sel = m ? halfk : bestk;
        idxArr[b * NFRM + gf] = sel + 1;      // = chosen lag
    }
}

// ---------------- Kernel 2: 30-wide median filter + pitch ----------------
__global__ __launch_bounds__(256) void med_kernel(const int* __restrict__ idxArr,
                                                  float* __restrict__ out) {
    int gid = blockIdx.x * 256 + threadIdx.x;
    if (gid >= 8 * OUTW) return;
    int b = gid / OUTW;
    int i = gid - b * OUTW;
    float o = 0.0f;
    if (i < MEDLEN) {
        const int* row = idxArr + b * NFRM;
        int vals[WINL];
        #pragma unroll
        for (int m = 0; m < WINL; ++m) {
            int sIdx = i + m - PADL;          // left pad = repeat idx[0]
            vals[m] = row[sIdx < 0 ? 0 : sIdx];
        }
        int med = vals[0];
        #pragma unroll
        for (int c = 0; c < WINL; ++c) {
            int cl = 0, ce = 0;
            #pragma unroll
            for (int m = 0; m < WINL; ++m) {
                cl += (vals[m] <  vals[c]) ? 1 : 0;
                ce += (vals[m] == vals[c]) ? 1 : 0;
            }
            if (cl <= 14 && 14 < cl + ce) med = vals[c];   // rank-14 = sorted[14]
        }
        o = 16000.0f / (1e-9f + (float)med);
    }
    out[gid] = o;
}

extern "C" void kernel_launch(void* const* d_in, const int* in_sizes, int n_in,
                              void* d_out, int out_size, void* d_ws, size_t ws_size,
                              hipStream_t stream) {
    const float* wav = (const float*)d_in[0];
    float* out = (float*)d_out;
    int* idxArr = (int*)d_ws;                 // 8*1879 ints = 60128 B

    dim3 gB(NBX, 8);                          // 235 x 8 blocks, 8 frames each
    hipLaunchKernelGGL(nccf_kernel, gB, dim3(256), 0, stream, wav, idxArr);

    int total = 8 * OUTW;
    hipLaunchKernelGGL(med_kernel, dim3((total + 255) / 256), dim3(256), 0, stream,
                       idxArr, out);
}

// Round 13
// 66.139 us; speedup vs baseline: 1.0925x; 1.0796x over previous
//
#include <hip/hip_runtime.h>

#define T_WPAD  962048   // reflect-padded waveform length (before zero tail)
#define T_RAW   960000
#define NFRM    1879
#define OUTW    1876
#define MEDLEN  1864
#define WINL    30
#define PADL    14
#define FPB     8        // frames per block
#define NBX     235      // ceil(NFRM / FPB)
#define XLEN    4296     // 7*512 + 705 + pad (float4-divisible)
#define X4LEN   1074

// Rotated inner body: window offset O (0/4/8/12), all indices compile-time.
// Reads w[(O+1)..(O+15) mod 16]; stores nx into w[O..O+3] (the retired slots).
#define NCCF_BODY(O, AUSE, ALOAD, KEXPR, QOUT, DO_LOAD_A, DO_STORE_W)           \
    {                                                                           \
        if (DO_LOAD_A) ALOAD = X4[aK + (KEXPR) + 1];                            \
        float4 nx;                                                              \
        if (DO_STORE_W) nx = X4[wBase + (KEXPR) + 4];                           \
        _Pragma("unroll")                                                       \
        for (int r = 0; r < 12; ++r) {                                          \
            acc[r] = fmaf(AUSE.x, w[(O + r + 1) & 15], acc[r]);                 \
            acc[r] = fmaf(AUSE.y, w[(O + r + 2) & 15], acc[r]);                 \
            acc[r] = fmaf(AUSE.z, w[(O + r + 3) & 15], acc[r]);                 \
            acc[r] = fmaf(AUSE.w, w[(O + r + 4) & 15], acc[r]);                 \
        }                                                                       \
        if (DO_STORE_W) {                                                       \
            QOUT = fmaf(nx.x, nx.x, fmaf(nx.y, nx.y, fmaf(nx.z, nx.z, nx.w * nx.w))); \
            w[(O + 0) & 15] = nx.x; w[(O + 1) & 15] = nx.y;                     \
            w[(O + 2) & 15] = nx.z; w[(O + 3) & 15] = nx.w;                     \
        }                                                                       \
    }

// ---------------- Kernel 1: NCCF + per-frame lag selection ----------------
// 128 thr = 2 waves; each wave handles FOUR frames (one per 16-lane group).
// g = lane>>4 picks frame-in-wave, s = lane&15 owns lags 12s+1..12s+12.
// Inner loop: hand-rotated 16-float register window (4 bodies, offsets
// 0/4/8/12) -> ZERO shift/copy instructions by construction; A operand
// alternates two registers by parity. T (sumsq) updated once per 4-step
// group: f32 quad sums, one f64 cvt+add. 2 ds_read_b128 + 48 FMA per body.
__global__ __launch_bounds__(128) void nccf_kernel(const float* __restrict__ wav,
                                                   int* __restrict__ idxArr) {
    const int bx   = blockIdx.x;
    const int b    = blockIdx.y;
    const int tid  = threadIdx.x;
    const int wave = tid >> 6;           // 0..1
    const int lane = tid & 63;
    const int g    = lane >> 4;          // frame within wave (0..3)
    const int s    = lane & 15;          // lag-group lane (0..15)

    __shared__ __align__(16) float X[XLEN];

    const long a0 = (long)bx * (FPB * 512);
    const float* wrow = wav + (long)b * T_RAW;

    // Stage wp[a0 .. a0+XLEN): vectorized fast path for interior blocks.
    if (bx >= 1 && bx <= NBX - 2) {
        const float4* src = (const float4*)(wrow + (a0 - 1024));
        float4* dst = (float4*)X;
        for (int i = tid; i < X4LEN; i += 128) dst[i] = src[i];
    } else {
        for (int i = tid; i < XLEN; i += 128) {
            float v = 0.0f;
            long t = a0 + i;
            if (t < T_WPAD) {
                long u = t - 1024;
                if (u < 0) u = -u;
                if (u >= T_RAW) u = 2L * (T_RAW - 1) - u;
                v = wrow[u];
            }
            X[i] = v;
        }
    }
    __syncthreads();

    const int F  = wave * 4 + g;         // frame within block (0..7)
    const int gf = bx * FPB + F;         // global frame
    const bool valid = (gf < NFRM);

    float acc[12];
    #pragma unroll
    for (int r = 0; r < 12; ++r) acc[r] = 0.0f;
    float sq[12];                         // X[12s+j]^2, j=0..11
    double Tcur = 0.0;
    double T512 = 0.0;
    float w[16];

    {
        const float4* X4 = (const float4*)X;
        const int aK    = F * 128;            // float4 index of Xf[0]
        const int wBase = aK + 3 * s;         // float4 index of Xf[12s]

        #pragma unroll
        for (int d = 0; d < 4; ++d) {
            float4 t4 = X4[wBase + d];
            w[4 * d] = t4.x; w[4 * d + 1] = t4.y; w[4 * d + 2] = t4.z; w[4 * d + 3] = t4.w;
        }
        #pragma unroll
        for (int j = 0; j < 12; ++j) sq[j] = w[j] * w[j];
        #pragma unroll
        for (int j = 0; j < 16; ++j) Tcur += (double)(w[j] * w[j]);   // T(16)

        float4 Aev = X4[aK];                  // A(0)
        float4 Aod;
        float q0, q1, q2, q3;

        // Groups 0..30: k = 4kg..4kg+3, with T tracking (covers T(512)).
        #pragma unroll 2
        for (int kg = 0; kg < 31; ++kg) {
            const int k4 = kg * 4;
            NCCF_BODY(0,  Aev, Aod, k4 + 0, q0, true, true)
            NCCF_BODY(4,  Aod, Aev, k4 + 1, q1, true, true)
            NCCF_BODY(8,  Aev, Aod, k4 + 2, q2, true, true)
            NCCF_BODY(12, Aod, Aev, k4 + 3, q3, true, true)
            Tcur += (double)((q0 + q1) + (q2 + q3));
        }
        T512 = Tcur;                          // T(512)

        // Tail group: k = 124..127, no T tracking; k=127 has no load/store.
        NCCF_BODY(0,  Aev, Aod, 124, q0, true,  true)
        NCCF_BODY(4,  Aod, Aev, 125, q1, true,  true)
        NCCF_BODY(8,  Aev, Aod, 126, q2, true,  true)
        NCCF_BODY(12, Aod, Aod, 127, q3, false, false)
    }
    // Physical w[0..11] now = X[12s+512 .. 12s+524) (trailing elements).

    // Epilogue: per-lag norms from registers. q(r) = T(512+r) - T(r).
    double qv[12];
    {
        double Thi = T512, Tlo = 0.0;
        #pragma unroll
        for (int r = 1; r <= 12; ++r) {
            float eh = w[r - 1];              // X[12s+512+(r-1)]
            Thi += (double)(eh * eh);
            Tlo += (double)sq[r - 1];
            qv[r - 1] = Thi - Tlo;
        }
    }
    double s1d = __shfl(T512, 0, 16);         // frame sumsq P[512] (s=0 lane)

    // Per-lane selection over its 12 lags (fp32, np-like first-max ties).
    float bestv = -1e30f, halfv = -1e30f;
    int bestk = 1 << 30, halfk = 1 << 30;
    {
        float s1 = 1e-9f + sqrtf((float)s1d);
        float s1n = s1 * s1;
        #pragma unroll
        for (int r = 1; r <= 12; ++r) {
            int lag  = 12 * s + r;
            int kidx = lag - 1;               // nccf lag index 0..191
            if (kidx <= 188) {
                float s2 = 1e-9f + sqrtf((float)qv[r - 1]);
                float v  = acc[r - 1] / s1n / (s2 * s2);
                if (kidx >= 5) {
                    if (v > bestv) { bestv = v; bestk = kidx; }
                    if (kidx <= 93 && v > halfv) { halfv = v; halfk = kidx; }
                }
            }
        }
    }

    // 16-lane (max, first-argmax) reduction for both slices.
    #pragma unroll
    for (int off = 8; off >= 1; off >>= 1) {
        float ov = __shfl_xor(bestv, off, 16); int ok = __shfl_xor(bestk, off, 16);
        if (ov > bestv || (ov == bestv && ok < bestk)) { bestv = ov; bestk = ok; }
        float hv = __shfl_xor(halfv, off, 16); int hk = __shfl_xor(halfk, off, 16);
        if (hv > halfv || (hv == halfv && hk < halfk)) { halfv = hv; halfk = hk; }
    }

    if (valid && s == 0) {
        bool m = (halfv > 0.99f * bestv);
        int sel = m ? halfk : bestk;
        idxArr[b * NFRM + gf] = sel + 1;      // = chosen lag
    }
}

// ---------------- Kernel 2: 30-wide median filter + pitch ----------------
__global__ __launch_bounds__(256) void med_kernel(const int* __restrict__ idxArr,
                                                  float* __restrict__ out) {
    int gid = blockIdx.x * 256 + threadIdx.x;
    if (gid >= 8 * OUTW) return;
    int b = gid / OUTW;
    int i = gid - b * OUTW;
    float o = 0.0f;
    if (i < MEDLEN) {
        const int* row = idxArr + b * NFRM;
        int vals[WINL];
        #pragma unroll
        for (int m = 0; m < WINL; ++m) {
            int sIdx = i + m - PADL;          // left pad = repeat idx[0]
            vals[m] = row[sIdx < 0 ? 0 : sIdx];
        }
        int med = vals[0];
        #pragma unroll
        for (int c = 0; c < WINL; ++c) {
            int cl = 0, ce = 0;
            #pragma unroll
            for (int m = 0; m < WINL; ++m) {
                cl += (vals[m] <  vals[c]) ? 1 : 0;
                ce += (vals[m] == vals[c]) ? 1 : 0;
            }
            if (cl <= 14 && 14 < cl + ce) med = vals[c];   // rank-14 = sorted[14]
        }
        o = 16000.0f / (1e-9f + (float)med);
    }
    out[gid] = o;
}

extern "C" void kernel_launch(void* const* d_in, const int* in_sizes, int n_in,
                              void* d_out, int out_size, void* d_ws, size_t ws_size,
                              hipStream_t stream) {
    const float* wav = (const float*)d_in[0];
    float* out = (float*)d_out;
    int* idxArr = (int*)d_ws;                 // 8*1879 ints = 60128 B

    dim3 gB(NBX, 8);                          // 235 x 8 blocks, 8 frames each
    hipLaunchKernelGGL(nccf_kernel, gB, dim3(128), 0, stream, wav, idxArr);

    int total = 8 * OUTW;
    hipLaunchKernelGGL(med_kernel, dim3((total + 255) / 256), dim3(256), 0, stream,
                       idxArr, out);
}